// Round 7
// baseline (996.164 us; speedup 1.0000x reference)
//
#include <hip/hip_runtime.h>
#include <hip/hip_bf16.h>
#include <math.h>

// ---------------------------------------------------------------------------
// GCNWithEdge, algebraically folded + bucketed LDS aggregation. FP32 in/out.
//   xWs[n]   = dinv[n] * (x @ W1)[n]            (bf16, dinv folded in)
//   h1[n]    = relu(dinv[n]*(sum_{s->n} xWs[s] + xWs[n]) + b1)
//   Qs[n][c] = dinv[n] * (h1[n] . U[:,c]),  U = W2 @ fcW1[0:64,:]
//   P[n][c]  = dinv[n] * (sum_{s->n} Qs[s][c] + Qs[n][c])
//   z[e][c]  = P[s]-P[d] + a0*fcW1[64,c] + a1*fcW1[65,c] + E0t[a2]+E1t[a3]+fcb1
//   out = log_softmax( relu(z) @ fcW2 + fcb2 )
// R6: CSR (col/rp) eliminated. Edges bucket-sorted into packed pairs
// ((dst&255)<<17 | src); conv1 = per-bucket 64KB-LDS atomic aggregation (kE),
// conv2 = per-bucket 2KB-LDS aggregation (kC2). dinv folded into xWs/Qs kills
// the per-edge random dinv lookup (~100MB L2 traffic).
// ---------------------------------------------------------------------------

typedef __hip_bfloat16 bf16;
#define NBLK 256          // blocks for kA/kB (must match between them)

// ---- kA: per-(bucket,block) histogram ----
__global__ __launch_bounds__(256) void kA(const int* __restrict__ dst,
                                          int* __restrict__ cntm,
                                          int E, int chunk, int NB) {
    __shared__ int h[512];
    int blk = blockIdx.x;
    for (int i = threadIdx.x; i < NB; i += 256) h[i] = 0;
    __syncthreads();
    int lo = blk * chunk, hi = min(E, lo + chunk);
    for (int e = lo + threadIdx.x; e < hi; e += 256)
        atomicAdd(&h[dst[e] >> 8], 1);
    __syncthreads();
    for (int i = threadIdx.x; i < NB; i += 256)
        cntm[(size_t)i * NBLK + blk] = h[i];
}

// ---- exclusive scan of cntm (3 kernels, M = NB*NBLK) ----
__global__ void k_mscan1(int* __restrict__ a, int* __restrict__ part, int M) {
    __shared__ int s[256];
    int i = blockIdx.x * 256 + threadIdx.x;
    int v = (i < M) ? a[i] : 0;
    s[threadIdx.x] = v;
    int x = v;
    for (int off = 1; off < 256; off <<= 1) {
        __syncthreads();
        int add = (threadIdx.x >= off) ? s[threadIdx.x - off] : 0;
        __syncthreads();
        x += add;
        s[threadIdx.x] = x;
    }
    if (i < M) a[i] = x - v;
    __syncthreads();
    if (threadIdx.x == 255) part[blockIdx.x] = s[255];
}

__global__ void k_scan2(int* __restrict__ part, int B) {
    __shared__ int s[512];
    int t = threadIdx.x;
    int v = (t < B) ? part[t] : 0;
    s[t] = v;
    int x = v;
    for (int off = 1; off < 512; off <<= 1) {
        __syncthreads();
        int add = (t >= off) ? s[t - off] : 0;
        __syncthreads();
        x += add;
        s[t] = x;
    }
    if (t < B) part[t] = x - v;
}

__global__ void k_mscan3(int* __restrict__ a, const int* __restrict__ part, int M) {
    int i = blockIdx.x * 256 + threadIdx.x;
    if (i < M) a[i] += part[blockIdx.x];
}

// ---- kB: place packed pairs into bucket-major array (block-private ranges) ----
__global__ __launch_bounds__(256) void kB(const int* __restrict__ src,
                                          const int* __restrict__ dst,
                                          const int* __restrict__ cntm,
                                          int* __restrict__ pairs,
                                          int E, int chunk, int NB) {
    __shared__ int off[512];
    int blk = blockIdx.x;
    for (int i = threadIdx.x; i < NB; i += 256)
        off[i] = cntm[(size_t)i * NBLK + blk];
    __syncthreads();
    int lo = blk * chunk, hi = min(E, lo + chunk);
    for (int e = lo + threadIdx.x; e < hi; e += 256) {
        int d = dst[e];
        int pos = atomicAdd(&off[d >> 8], 1);
        pairs[pos] = ((d & 255) << 17) | src[e];
    }
}

// ---- kD: per-bucket in-degree count -> dinv ----
__global__ __launch_bounds__(256) void kD(const int* __restrict__ cntm,
                                          const int* __restrict__ pairs,
                                          float* __restrict__ dinv,
                                          int N, int E, int NB) {
    __shared__ int cnt[256];
    int b = blockIdx.x, t = threadIdx.x;
    int base = cntm[(size_t)b * NBLK];
    int end  = (b == NB - 1) ? E : cntm[(size_t)(b + 1) * NBLK];
    cnt[t] = 0;
    __syncthreads();
    for (int j = base + t; j < end; j += 256)
        atomicAdd(&cnt[pairs[j] >> 17], 1);
    __syncthreads();
    int n = (b << 8) + t;
    if (n < N) dinv[n] = rsqrtf((float)cnt[t] + 1.0f);   // +1 self-loop
}

// ---------------- tiny folded tables ----------------
__global__ void k_small(const float* __restrict__ W2,
                        const float* __restrict__ emb0, const float* __restrict__ emb1,
                        const float* __restrict__ fcW1, const float* __restrict__ fcb1,
                        const float* __restrict__ fcW2, const float* __restrict__ fcb2,
                        float* __restrict__ U, float* __restrict__ E0t,
                        float* __restrict__ E1t, float* __restrict__ C) {
    int t = threadIdx.x; // 64 threads
    for (int c = 0; c < 2; ++c) {
        float s = 0.f;
        for (int j = 0; j < 64; ++j) s += W2[t * 64 + j] * fcW1[j * 2 + c];
        U[t * 2 + c] = s;
    }
    if (t < 20) {
        for (int c = 0; c < 2; ++c) {
            float s0 = 0.f, s1 = 0.f;
            for (int k = 0; k < 32; ++k) {
                s0 += emb0[t * 32 + k] * fcW1[(66 + k) * 2 + c];
                s1 += emb1[t * 32 + k] * fcW1[(98 + k) * 2 + c];
            }
            E0t[t * 2 + c] = s0;
            E1t[t * 2 + c] = s1;
        }
    }
    if (t == 0) {
        C[0] = fcb1[0];                           // b2 cancels in h2[s]-h2[d]
        C[1] = fcb1[1];
        C[2] = fcW1[64 * 2 + 0]; C[3] = fcW1[64 * 2 + 1];
        C[4] = fcW1[65 * 2 + 0]; C[5] = fcW1[65 * 2 + 1];
        C[6] = fcW2[0]; C[7] = fcW2[1];
        C[8] = fcW2[2]; C[9] = fcW2[3];
        C[10] = fcb2[0]; C[11] = fcb2[1];
    }
}

// ---------------- xWs = dinv * (x @ W1), LDS-tiled 4x4 blocking ----------------
__global__ __launch_bounds__(256) void k_gemm1(const float* __restrict__ x,
                                               const float* __restrict__ W1,
                                               const float* __restrict__ dinv,
                                               bf16* __restrict__ xWs, int N) {
    __shared__ __align__(16) float xs[64][68];
    __shared__ __align__(16) float Ws[64][64];
    int tid = threadIdx.x;
    int n0 = blockIdx.x * 64;
    for (int i = tid; i < 4096; i += 256) Ws[i >> 6][i & 63] = W1[i];
    for (int i = tid; i < 4096; i += 256) {
        int node = i >> 6, k = i & 63;
        float v = (n0 + node < N) ? x[(size_t)(n0 + node) * 64 + k] : 0.f;
        xs[k][node] = v;
    }
    __syncthreads();
    int tr = tid >> 4;
    int tc = tid & 15;
    float acc[4][4] = {};
#pragma unroll 8
    for (int k = 0; k < 64; ++k) {
        float4 xv = *(const float4*)&xs[k][tr * 4];
        float4 wv = *(const float4*)&Ws[k][tc * 4];
        acc[0][0] = fmaf(xv.x, wv.x, acc[0][0]);
        acc[0][1] = fmaf(xv.x, wv.y, acc[0][1]);
        acc[0][2] = fmaf(xv.x, wv.z, acc[0][2]);
        acc[0][3] = fmaf(xv.x, wv.w, acc[0][3]);
        acc[1][0] = fmaf(xv.y, wv.x, acc[1][0]);
        acc[1][1] = fmaf(xv.y, wv.y, acc[1][1]);
        acc[1][2] = fmaf(xv.y, wv.z, acc[1][2]);
        acc[1][3] = fmaf(xv.y, wv.w, acc[1][3]);
        acc[2][0] = fmaf(xv.z, wv.x, acc[2][0]);
        acc[2][1] = fmaf(xv.z, wv.y, acc[2][1]);
        acc[2][2] = fmaf(xv.z, wv.z, acc[2][2]);
        acc[2][3] = fmaf(xv.z, wv.w, acc[2][3]);
        acc[3][0] = fmaf(xv.w, wv.x, acc[3][0]);
        acc[3][1] = fmaf(xv.w, wv.y, acc[3][1]);
        acc[3][2] = fmaf(xv.w, wv.z, acc[3][2]);
        acc[3][3] = fmaf(xv.w, wv.w, acc[3][3]);
    }
#pragma unroll
    for (int i = 0; i < 4; ++i) {
        int node = n0 + tr * 4 + i;
        if (node < N) {
            float di = dinv[node];
            __hip_bfloat162 p0, p1;
            p0.x = __float2bfloat16(di * acc[i][0]);
            p0.y = __float2bfloat16(di * acc[i][1]);
            p1.x = __float2bfloat16(di * acc[i][2]);
            p1.y = __float2bfloat16(di * acc[i][3]);
            __hip_bfloat162* dst2 = (__hip_bfloat162*)&xWs[(size_t)node * 64 + tc * 4];
            dst2[0] = p0;
            dst2[1] = p1;
        }
    }
}

// ---- kE: fused conv1 aggregation (per-bucket 64KB LDS) + relu + projection ----
__global__ __launch_bounds__(256) void kE(const bf16* __restrict__ xWs,
                                          const int* __restrict__ cntm,
                                          const int* __restrict__ pairs,
                                          const float* __restrict__ dinv,
                                          const float* __restrict__ b1,
                                          const float* __restrict__ U,
                                          float* __restrict__ Qs,
                                          int N, int E, int NB) {
    __shared__ float agg[256 * 64];              // 64 KB
    int t = threadIdx.x, b = blockIdx.x;
    float4 z4 = {0.f, 0.f, 0.f, 0.f};
#pragma unroll
    for (int i = 0; i < 16; ++i)
        *(float4*)&agg[(i * 256 + t) * 4] = z4;
    __syncthreads();
    int base = cntm[(size_t)b * NBLK];
    int end  = (b == NB - 1) ? E : cntm[(size_t)(b + 1) * NBLK];
    int o = t & 63;
    int wv = t >> 6;
    for (int jb = base + wv * 64; jb < end; jb += 256) {
        int nn = min(64, end - jb);
        int pv = pairs[min(jb + o, E - 1)];
        int jj = 0;
        for (; jj + 8 <= nn; jj += 8) {
            int p0 = __shfl(pv, jj + 0);
            int p1 = __shfl(pv, jj + 1);
            int p2 = __shfl(pv, jj + 2);
            int p3 = __shfl(pv, jj + 3);
            int p4 = __shfl(pv, jj + 4);
            int p5 = __shfl(pv, jj + 5);
            int p6 = __shfl(pv, jj + 6);
            int p7 = __shfl(pv, jj + 7);
            float v0 = __bfloat162float(xWs[(size_t)(p0 & 0x1FFFF) * 64 + o]);
            float v1 = __bfloat162float(xWs[(size_t)(p1 & 0x1FFFF) * 64 + o]);
            float v2 = __bfloat162float(xWs[(size_t)(p2 & 0x1FFFF) * 64 + o]);
            float v3 = __bfloat162float(xWs[(size_t)(p3 & 0x1FFFF) * 64 + o]);
            float v4 = __bfloat162float(xWs[(size_t)(p4 & 0x1FFFF) * 64 + o]);
            float v5 = __bfloat162float(xWs[(size_t)(p5 & 0x1FFFF) * 64 + o]);
            float v6 = __bfloat162float(xWs[(size_t)(p6 & 0x1FFFF) * 64 + o]);
            float v7 = __bfloat162float(xWs[(size_t)(p7 & 0x1FFFF) * 64 + o]);
            atomicAdd(&agg[((p0 >> 17) << 6) + o], v0);
            atomicAdd(&agg[((p1 >> 17) << 6) + o], v1);
            atomicAdd(&agg[((p2 >> 17) << 6) + o], v2);
            atomicAdd(&agg[((p3 >> 17) << 6) + o], v3);
            atomicAdd(&agg[((p4 >> 17) << 6) + o], v4);
            atomicAdd(&agg[((p5 >> 17) << 6) + o], v5);
            atomicAdd(&agg[((p6 >> 17) << 6) + o], v6);
            atomicAdd(&agg[((p7 >> 17) << 6) + o], v7);
        }
        for (; jj < nn; ++jj) {
            int p = __shfl(pv, jj);
            float v = __bfloat162float(xWs[(size_t)(p & 0x1FFFF) * 64 + o]);
            atomicAdd(&agg[((p >> 17) << 6) + o], v);
        }
    }
    __syncthreads();
    // finalize: wave wv handles local nodes [wv*64, wv*64+64)
    for (int i = 0; i < 64; ++i) {
        int ln = (wv << 6) + i;
        int n = (b << 8) + ln;
        if (n >= N) break;
        float di = dinv[n];
        float self = __bfloat162float(xWs[(size_t)n * 64 + o]);
        float a = di * (agg[(ln << 6) + o] + self);
        float h = fmaxf(a + b1[o], 0.f);
        float q0 = h * U[o * 2 + 0];
        float q1 = h * U[o * 2 + 1];
#pragma unroll
        for (int mm = 32; mm; mm >>= 1) {
            q0 += __shfl_xor(q0, mm);
            q1 += __shfl_xor(q1, mm);
        }
        if (o == 0) {
            Qs[2 * n + 0] = di * q0;
            Qs[2 * n + 1] = di * q1;
        }
    }
}

// ---- kC2: conv2 per-bucket scalar aggregation -> P ----
__global__ __launch_bounds__(256) void kC2(const int* __restrict__ cntm,
                                           const int* __restrict__ pairs,
                                           const float* __restrict__ Qs,
                                           const float* __restrict__ dinv,
                                           float* __restrict__ P,
                                           int N, int E, int NB) {
    __shared__ float acc[512];
    int t = threadIdx.x, b = blockIdx.x;
    acc[2 * t] = 0.f;
    acc[2 * t + 1] = 0.f;
    __syncthreads();
    int base = cntm[(size_t)b * NBLK];
    int end  = (b == NB - 1) ? E : cntm[(size_t)(b + 1) * NBLK];
    for (int j = base + t; j < end; j += 256) {
        int p = pairs[j];
        float2 q = ((const float2*)Qs)[p & 0x1FFFF];
        int ld = p >> 17;
        atomicAdd(&acc[2 * ld + 0], q.x);
        atomicAdd(&acc[2 * ld + 1], q.y);
    }
    __syncthreads();
    int n = (b << 8) + t;
    if (n < N) {
        float di = dinv[n];
        float2 qs = ((const float2*)Qs)[n];
        P[2 * n + 0] = di * (acc[2 * t + 0] + qs.x);
        P[2 * n + 1] = di * (acc[2 * t + 1] + qs.y);
    }
}

// ---------------- per-edge epilogue -> fp32 out ----------------
__global__ void k_edge(const int* __restrict__ src, const int* __restrict__ dst,
                       const int* __restrict__ attr, const float* __restrict__ P,
                       const float* __restrict__ E0t, const float* __restrict__ E1t,
                       const float* __restrict__ C, float* __restrict__ out, int E) {
    int e = blockIdx.x * blockDim.x + threadIdx.x;
    if (e >= E) return;
    int s = src[e], d = dst[e];
    float a0 = (float)attr[e];
    float a1 = (float)attr[E + e];
    int i2 = attr[2 * E + e], i3 = attr[3 * E + e];
    const float2* P2 = (const float2*)P;
    float2 ps = P2[s], pd = P2[d];
    float z0 = ps.x - pd.x + a0 * C[2] + a1 * C[4] + E0t[i2 * 2 + 0] + E1t[i3 * 2 + 0] + C[0];
    float z1 = ps.y - pd.y + a0 * C[3] + a1 * C[5] + E0t[i2 * 2 + 1] + E1t[i3 * 2 + 1] + C[1];
    float r0 = fmaxf(z0, 0.f), r1 = fmaxf(z1, 0.f);
    float o0 = r0 * C[6] + r1 * C[8] + C[10];
    float o1 = r0 * C[7] + r1 * C[9] + C[11];
    float m = fmaxf(o0, o1);
    float lse = m + logf(expf(o0 - m) + expf(o1 - m));
    float2 res;
    res.x = o0 - lse;
    res.y = o1 - lse;
    ((float2*)out)[e] = res;
}

extern "C" void kernel_launch(void* const* d_in, const int* in_sizes, int n_in,
                              void* d_out, int out_size, void* d_ws, size_t ws_size,
                              hipStream_t stream) {
    const float* x    = (const float*)d_in[0];
    const int*   ei   = (const int*)d_in[1];
    const int*   ea   = (const int*)d_in[2];
    const float* W1   = (const float*)d_in[3];
    const float* b1   = (const float*)d_in[4];
    const float* W2   = (const float*)d_in[5];
    const float* emb0 = (const float*)d_in[7];
    const float* emb1 = (const float*)d_in[8];
    const float* fcW1 = (const float*)d_in[9];
    const float* fcb1 = (const float*)d_in[10];
    const float* fcW2 = (const float*)d_in[11];
    const float* fcb2 = (const float*)d_in[12];

    const int N = in_sizes[0] / 64;
    const int E = in_sizes[1] / 2;
    const int* src = ei;
    const int* dst = ei + E;
    const int NB = (N + 255) >> 8;                // buckets of 256 nodes (391)
    const int NBB = NB * NBLK;                    // count-matrix size (~100K)
    const int chunk = (E + NBLK - 1) / NBLK;
    const int BS = (NBB + 255) / 256;             // scan blocks (<=512)

    // ws layout (4-byte words), ~14.8 MB:
    char* wsb = (char*)d_ws;
    float* dinv = (float*)wsb;                             // N
    int*   cntm = (int*)(wsb + (size_t)4 * 100352);        // NBB
    int*   part = (int*)(wsb + (size_t)4 * 200704);        // 512
    float* U    = (float*)(wsb + (size_t)4 * 201216);      // 128
    float* E0t  = U + 128;                                 // 40
    float* E1t  = E0t + 40;                                // 40
    float* C    = E1t + 40;                                // 12
    float* Qs   = (float*)(wsb + (size_t)4 * 201728);      // 2N
    float* P    = (float*)(wsb + (size_t)4 * 402432);      // 2N
    bf16*  xWs  = (bf16*)(wsb + (size_t)4 * 603136);       // N*64 bf16 (12.8 MB)
    int*   pairs = (int*)d_out;                            // E ints; k_edge overwrites last

    k_small<<<1, 64, 0, stream>>>(W2, emb0, emb1, fcW1, fcb1, fcW2, fcb2,
                                  U, E0t, E1t, C);
    kA<<<NBLK, 256, 0, stream>>>(dst, cntm, E, chunk, NB);
    k_mscan1<<<BS, 256, 0, stream>>>(cntm, part, NBB);
    k_scan2<<<1, 512, 0, stream>>>(part, BS);
    k_mscan3<<<BS, 256, 0, stream>>>(cntm, part, NBB);
    kB<<<NBLK, 256, 0, stream>>>(src, dst, cntm, pairs, E, chunk, NB);
    kD<<<NB, 256, 0, stream>>>(cntm, pairs, dinv, N, E, NB);
    k_gemm1<<<(N + 63) / 64, 256, 0, stream>>>(x, W1, dinv, xWs, N);
    kE<<<NB, 256, 0, stream>>>(xWs, cntm, pairs, dinv, b1, U, Qs, N, E, NB);
    kC2<<<NB, 256, 0, stream>>>(cntm, pairs, Qs, dinv, P, N, E, NB);
    k_edge<<<(E + 255) / 256, 256, 0, stream>>>(src, dst, ea, P, E0t, E1t, C,
                                                (float*)d_out, E);
}

// Round 8
// 295.529 us; speedup vs baseline: 3.3708x; 3.3708x over previous
//
#include <hip/hip_runtime.h>
#include <hip/hip_bf16.h>
#include <math.h>

// ---------------------------------------------------------------------------
// GCNWithEdge, algebraically folded + bucketed CSR gather. FP32 in/out.
//   xWs[n]   = dinv[n] * (x @ W1)[n]          (bf16, dinv folded in)
//   h1[n]    = relu(dinv[n]*(sum_{s->n} xWs[s] + xWs[n]) + b1)
//   Qs[n][c] = dinv[n] * (h1[n] . U[:,c]),  U = W2 @ fcW1[0:64,:]
//   P[n][c]  = dinv[n] * (sum_{s->n} Qs[s][c] + Qs[n][c])
//   z[e][c]  = P[s]-P[d] + a0*fcW1[64,c] + a1*fcW1[65,c] + E0t[a2]+E1t[a3]+fcb1
//   out = log_softmax( relu(z) @ fcW2 + fcb2 )
// R7 post-mortem: 64KB-LDS fused aggregation = occupancy cliff (14.8% occ,
// 3.6% VALU) -> 996us. Reverted to R6 CSR-gather structure (70% occ);
// kept R7's dinv folding (halves random loads/edge) + 16-deep MLP unroll.
// ---------------------------------------------------------------------------

typedef __hip_bfloat16 bf16;
#define NBLK 256          // blocks for kA/kB (must match between them)

// ---- kA: per-(bucket,block) histogram ----
__global__ __launch_bounds__(256) void kA(const int* __restrict__ dst,
                                          int* __restrict__ cntm,
                                          int E, int chunk, int NB) {
    __shared__ int h[512];
    int blk = blockIdx.x;
    for (int i = threadIdx.x; i < NB; i += 256) h[i] = 0;
    __syncthreads();
    int lo = blk * chunk, hi = min(E, lo + chunk);
    for (int e = lo + threadIdx.x; e < hi; e += 256)
        atomicAdd(&h[dst[e] >> 8], 1);
    __syncthreads();
    for (int i = threadIdx.x; i < NB; i += 256)
        cntm[(size_t)i * NBLK + blk] = h[i];
}

// ---- exclusive scan of cntm (3 kernels, M = NB*NBLK) ----
__global__ void k_mscan1(int* __restrict__ a, int* __restrict__ part, int M) {
    __shared__ int s[256];
    int i = blockIdx.x * 256 + threadIdx.x;
    int v = (i < M) ? a[i] : 0;
    s[threadIdx.x] = v;
    int x = v;
    for (int off = 1; off < 256; off <<= 1) {
        __syncthreads();
        int add = (threadIdx.x >= off) ? s[threadIdx.x - off] : 0;
        __syncthreads();
        x += add;
        s[threadIdx.x] = x;
    }
    if (i < M) a[i] = x - v;
    __syncthreads();
    if (threadIdx.x == 255) part[blockIdx.x] = s[255];
}

__global__ void k_scan2(int* __restrict__ part, int B) {
    __shared__ int s[512];
    int t = threadIdx.x;
    int v = (t < B) ? part[t] : 0;
    s[t] = v;
    int x = v;
    for (int off = 1; off < 512; off <<= 1) {
        __syncthreads();
        int add = (t >= off) ? s[t - off] : 0;
        __syncthreads();
        x += add;
        s[t] = x;
    }
    if (t < B) part[t] = x - v;
}

__global__ void k_mscan3(int* __restrict__ a, const int* __restrict__ part, int M) {
    int i = blockIdx.x * 256 + threadIdx.x;
    if (i < M) a[i] += part[blockIdx.x];
}

// ---- kB: place packed pairs into bucket-major array (block-private ranges) ----
__global__ __launch_bounds__(256) void kB(const int* __restrict__ src,
                                          const int* __restrict__ dst,
                                          const int* __restrict__ cntm,
                                          int* __restrict__ pairs,
                                          int E, int chunk, int NB) {
    __shared__ int off[512];
    int blk = blockIdx.x;
    for (int i = threadIdx.x; i < NB; i += 256)
        off[i] = cntm[(size_t)i * NBLK + blk];
    __syncthreads();
    int lo = blk * chunk, hi = min(E, lo + chunk);
    for (int e = lo + threadIdx.x; e < hi; e += 256) {
        int d = dst[e];
        int pos = atomicAdd(&off[d >> 8], 1);
        pairs[pos] = ((d & 255) << 17) | src[e];
    }
}

// ---- kC: per-bucket CSR finalize: dinv, rp, col (all local/coalesced) ----
__global__ __launch_bounds__(256) void kC(const int* __restrict__ cntm,
                                          const int* __restrict__ pairs,
                                          int* __restrict__ col, int* __restrict__ rp,
                                          float* __restrict__ dinv,
                                          int N, int E, int NB) {
    __shared__ int cnt[256];
    __shared__ int s[256];
    int b = blockIdx.x, t = threadIdx.x;
    int n0 = b << 8;
    int nn = min(256, N - n0);
    int base = cntm[(size_t)b * NBLK];
    int end  = (b == NB - 1) ? E : cntm[(size_t)(b + 1) * NBLK];
    cnt[t] = 0;
    __syncthreads();
    for (int j = base + t; j < end; j += 256)
        atomicAdd(&cnt[pairs[j] >> 17], 1);
    __syncthreads();
    int v = cnt[t];
    if (t < nn) dinv[n0 + t] = rsqrtf((float)v + 1.0f);   // +1 self-loop
    s[t] = v;
    int x = v;
    for (int off = 1; off < 256; off <<= 1) {
        __syncthreads();
        int add = (t >= off) ? s[t - off] : 0;
        __syncthreads();
        x += add;
        s[t] = x;
    }
    __syncthreads();
    int excl = x - v;
    if (t < nn) rp[n0 + t] = base + excl;
    cnt[t] = base + excl;                                 // cursor
    __syncthreads();
    for (int j = base + t; j < end; j += 256) {
        int v2 = pairs[j];
        int pos = atomicAdd(&cnt[v2 >> 17], 1);
        col[pos] = v2 & 0x1FFFF;
    }
    if (b == NB - 1 && t == 0) rp[N] = E;
}

// ---------------- tiny folded tables ----------------
__global__ void k_small(const float* __restrict__ W2,
                        const float* __restrict__ emb0, const float* __restrict__ emb1,
                        const float* __restrict__ fcW1, const float* __restrict__ fcb1,
                        const float* __restrict__ fcW2, const float* __restrict__ fcb2,
                        float* __restrict__ U, float* __restrict__ E0t,
                        float* __restrict__ E1t, float* __restrict__ C) {
    int t = threadIdx.x; // 64 threads
    for (int c = 0; c < 2; ++c) {
        float s = 0.f;
        for (int j = 0; j < 64; ++j) s += W2[t * 64 + j] * fcW1[j * 2 + c];
        U[t * 2 + c] = s;
    }
    if (t < 20) {
        for (int c = 0; c < 2; ++c) {
            float s0 = 0.f, s1 = 0.f;
            for (int k = 0; k < 32; ++k) {
                s0 += emb0[t * 32 + k] * fcW1[(66 + k) * 2 + c];
                s1 += emb1[t * 32 + k] * fcW1[(98 + k) * 2 + c];
            }
            E0t[t * 2 + c] = s0;
            E1t[t * 2 + c] = s1;
        }
    }
    if (t == 0) {
        C[0] = fcb1[0];                           // b2 cancels in h2[s]-h2[d]
        C[1] = fcb1[1];
        C[2] = fcW1[64 * 2 + 0]; C[3] = fcW1[64 * 2 + 1];
        C[4] = fcW1[65 * 2 + 0]; C[5] = fcW1[65 * 2 + 1];
        C[6] = fcW2[0]; C[7] = fcW2[1];
        C[8] = fcW2[2]; C[9] = fcW2[3];
        C[10] = fcb2[0]; C[11] = fcb2[1];
    }
}

// ---------------- xWs = dinv * (x @ W1), LDS-tiled 4x4 blocking ----------------
__global__ __launch_bounds__(256) void k_gemm1(const float* __restrict__ x,
                                               const float* __restrict__ W1,
                                               const float* __restrict__ dinv,
                                               bf16* __restrict__ xWs, int N) {
    __shared__ __align__(16) float xs[64][68];
    __shared__ __align__(16) float Ws[64][64];
    int tid = threadIdx.x;
    int n0 = blockIdx.x * 64;
    for (int i = tid; i < 4096; i += 256) Ws[i >> 6][i & 63] = W1[i];
    for (int i = tid; i < 4096; i += 256) {
        int node = i >> 6, k = i & 63;
        float v = (n0 + node < N) ? x[(size_t)(n0 + node) * 64 + k] : 0.f;
        xs[k][node] = v;
    }
    __syncthreads();
    int tr = tid >> 4;
    int tc = tid & 15;
    float acc[4][4] = {};
#pragma unroll 8
    for (int k = 0; k < 64; ++k) {
        float4 xv = *(const float4*)&xs[k][tr * 4];
        float4 wv = *(const float4*)&Ws[k][tc * 4];
        acc[0][0] = fmaf(xv.x, wv.x, acc[0][0]);
        acc[0][1] = fmaf(xv.x, wv.y, acc[0][1]);
        acc[0][2] = fmaf(xv.x, wv.z, acc[0][2]);
        acc[0][3] = fmaf(xv.x, wv.w, acc[0][3]);
        acc[1][0] = fmaf(xv.y, wv.x, acc[1][0]);
        acc[1][1] = fmaf(xv.y, wv.y, acc[1][1]);
        acc[1][2] = fmaf(xv.y, wv.z, acc[1][2]);
        acc[1][3] = fmaf(xv.y, wv.w, acc[1][3]);
        acc[2][0] = fmaf(xv.z, wv.x, acc[2][0]);
        acc[2][1] = fmaf(xv.z, wv.y, acc[2][1]);
        acc[2][2] = fmaf(xv.z, wv.z, acc[2][2]);
        acc[2][3] = fmaf(xv.z, wv.w, acc[2][3]);
        acc[3][0] = fmaf(xv.w, wv.x, acc[3][0]);
        acc[3][1] = fmaf(xv.w, wv.y, acc[3][1]);
        acc[3][2] = fmaf(xv.w, wv.z, acc[3][2]);
        acc[3][3] = fmaf(xv.w, wv.w, acc[3][3]);
    }
#pragma unroll
    for (int i = 0; i < 4; ++i) {
        int node = n0 + tr * 4 + i;
        if (node < N) {
            float di = dinv[node];
            __hip_bfloat162 p0, p1;
            p0.x = __float2bfloat16(di * acc[i][0]);
            p0.y = __float2bfloat16(di * acc[i][1]);
            p1.x = __float2bfloat16(di * acc[i][2]);
            p1.y = __float2bfloat16(di * acc[i][3]);
            __hip_bfloat162* dst2 = (__hip_bfloat162*)&xWs[(size_t)node * 64 + tc * 4];
            dst2[0] = p0;
            dst2[1] = p1;
        }
    }
}

// ---- conv1 gather (MLP-16, no per-edge dinv) + relu + 64->2 projection ----
__global__ __launch_bounds__(256) void k_gather1(
        const bf16* __restrict__ xWs, const float* __restrict__ dinv,
        const int* __restrict__ rp, const int* __restrict__ col,
        const float* __restrict__ b1, const float* __restrict__ U,
        float* __restrict__ Qs, int N, int E) {
    int wid = (blockIdx.x * 256 + threadIdx.x) >> 6;
    int o = threadIdx.x & 63;
    if (wid >= N) return;
    float acc = __bfloat162float(xWs[(size_t)wid * 64 + o]);  // self (x di later)
    int beg = rp[wid], end = rp[wid + 1];
    for (int base = beg; base < end; base += 64) {
        int nn = min(64, end - base);
        int colv = col[min(base + o, E - 1)];
        int jj = 0;
        for (; jj + 16 <= nn; jj += 16) {
            int m0 = __shfl(colv, jj + 0);
            int m1 = __shfl(colv, jj + 1);
            int m2 = __shfl(colv, jj + 2);
            int m3 = __shfl(colv, jj + 3);
            int m4 = __shfl(colv, jj + 4);
            int m5 = __shfl(colv, jj + 5);
            int m6 = __shfl(colv, jj + 6);
            int m7 = __shfl(colv, jj + 7);
            int m8 = __shfl(colv, jj + 8);
            int m9 = __shfl(colv, jj + 9);
            int mA = __shfl(colv, jj + 10);
            int mB = __shfl(colv, jj + 11);
            int mC = __shfl(colv, jj + 12);
            int mD = __shfl(colv, jj + 13);
            int mE = __shfl(colv, jj + 14);
            int mF = __shfl(colv, jj + 15);
            float v0 = __bfloat162float(xWs[(size_t)m0 * 64 + o]);
            float v1 = __bfloat162float(xWs[(size_t)m1 * 64 + o]);
            float v2 = __bfloat162float(xWs[(size_t)m2 * 64 + o]);
            float v3 = __bfloat162float(xWs[(size_t)m3 * 64 + o]);
            float v4 = __bfloat162float(xWs[(size_t)m4 * 64 + o]);
            float v5 = __bfloat162float(xWs[(size_t)m5 * 64 + o]);
            float v6 = __bfloat162float(xWs[(size_t)m6 * 64 + o]);
            float v7 = __bfloat162float(xWs[(size_t)m7 * 64 + o]);
            float v8 = __bfloat162float(xWs[(size_t)m8 * 64 + o]);
            float v9 = __bfloat162float(xWs[(size_t)m9 * 64 + o]);
            float vA = __bfloat162float(xWs[(size_t)mA * 64 + o]);
            float vB = __bfloat162float(xWs[(size_t)mB * 64 + o]);
            float vC = __bfloat162float(xWs[(size_t)mC * 64 + o]);
            float vD = __bfloat162float(xWs[(size_t)mD * 64 + o]);
            float vE = __bfloat162float(xWs[(size_t)mE * 64 + o]);
            float vF = __bfloat162float(xWs[(size_t)mF * 64 + o]);
            acc += ((v0 + v1) + (v2 + v3)) + ((v4 + v5) + (v6 + v7))
                 + ((v8 + v9) + (vA + vB)) + ((vC + vD) + (vE + vF));
        }
        for (; jj < nn; ++jj) {
            int m = __shfl(colv, jj);
            acc += __bfloat162float(xWs[(size_t)m * 64 + o]);
        }
    }
    float di = dinv[wid];
    float h = fmaxf(fmaf(di, acc, b1[o]), 0.f);
    float q0 = h * U[o * 2 + 0];
    float q1 = h * U[o * 2 + 1];
#pragma unroll
    for (int mm = 32; mm; mm >>= 1) {
        q0 += __shfl_xor(q0, mm);
        q1 += __shfl_xor(q1, mm);
    }
    if (o == 0) {
        Qs[2 * wid + 0] = di * q0;
        Qs[2 * wid + 1] = di * q1;
    }
}

// ---- conv2 scalar gather (Qs pre-scaled; computes self-term too) ----
__global__ void k_gather2(const float* __restrict__ dinv, const int* __restrict__ rp,
                          const int* __restrict__ col, const float* __restrict__ Qs,
                          float* __restrict__ P, int N) {
    int n = blockIdx.x * blockDim.x + threadIdx.x;
    if (n >= N) return;
    float2 self = ((const float2*)Qs)[n];
    float p0 = self.x, p1 = self.y;
    int beg = rp[n], end = rp[n + 1];
    int j = beg;
    for (; j + 4 <= end; j += 4) {
        int m0 = col[j + 0], m1 = col[j + 1], m2 = col[j + 2], m3 = col[j + 3];
        float2 q0 = ((const float2*)Qs)[m0];
        float2 q1 = ((const float2*)Qs)[m1];
        float2 q2 = ((const float2*)Qs)[m2];
        float2 q3 = ((const float2*)Qs)[m3];
        p0 += (q0.x + q1.x) + (q2.x + q3.x);
        p1 += (q0.y + q1.y) + (q2.y + q3.y);
    }
    for (; j < end; ++j) {
        float2 q = ((const float2*)Qs)[col[j]];
        p0 += q.x;
        p1 += q.y;
    }
    float di = dinv[n];
    P[2 * n + 0] = di * p0;
    P[2 * n + 1] = di * p1;
}

// ---------------- per-edge epilogue -> fp32 out ----------------
__global__ void k_edge(const int* __restrict__ src, const int* __restrict__ dst,
                       const int* __restrict__ attr, const float* __restrict__ P,
                       const float* __restrict__ E0t, const float* __restrict__ E1t,
                       const float* __restrict__ C, float* __restrict__ out, int E) {
    int e = blockIdx.x * blockDim.x + threadIdx.x;
    if (e >= E) return;
    int s = src[e], d = dst[e];
    float a0 = (float)attr[e];
    float a1 = (float)attr[E + e];
    int i2 = attr[2 * E + e], i3 = attr[3 * E + e];
    const float2* P2 = (const float2*)P;
    float2 ps = P2[s], pd = P2[d];
    float z0 = ps.x - pd.x + a0 * C[2] + a1 * C[4] + E0t[i2 * 2 + 0] + E1t[i3 * 2 + 0] + C[0];
    float z1 = ps.y - pd.y + a0 * C[3] + a1 * C[5] + E0t[i2 * 2 + 1] + E1t[i3 * 2 + 1] + C[1];
    float r0 = fmaxf(z0, 0.f), r1 = fmaxf(z1, 0.f);
    float o0 = r0 * C[6] + r1 * C[8] + C[10];
    float o1 = r0 * C[7] + r1 * C[9] + C[11];
    float m = fmaxf(o0, o1);
    float lse = m + logf(expf(o0 - m) + expf(o1 - m));
    float2 res;
    res.x = o0 - lse;
    res.y = o1 - lse;
    ((float2*)out)[e] = res;
}

extern "C" void kernel_launch(void* const* d_in, const int* in_sizes, int n_in,
                              void* d_out, int out_size, void* d_ws, size_t ws_size,
                              hipStream_t stream) {
    const float* x    = (const float*)d_in[0];
    const int*   ei   = (const int*)d_in[1];
    const int*   ea   = (const int*)d_in[2];
    const float* W1   = (const float*)d_in[3];
    const float* b1   = (const float*)d_in[4];
    const float* W2   = (const float*)d_in[5];
    const float* emb0 = (const float*)d_in[7];
    const float* emb1 = (const float*)d_in[8];
    const float* fcW1 = (const float*)d_in[9];
    const float* fcb1 = (const float*)d_in[10];
    const float* fcW2 = (const float*)d_in[11];
    const float* fcb2 = (const float*)d_in[12];

    const int N = in_sizes[0] / 64;
    const int E = in_sizes[1] / 2;
    const int* src = ei;
    const int* dst = ei + E;
    const int NB = (N + 255) >> 8;                // buckets of 256 nodes (391)
    const int NBB = NB * NBLK;                    // count-matrix size (~100K)
    const int chunk = (E + NBLK - 1) / NBLK;
    const int BS = (NBB + 255) / 256;             // scan blocks (<=512)

    // ws layout (4-byte words), ~15.6 MB:
    char* wsb = (char*)d_ws;
    float* dinv = (float*)wsb;                             // N
    int*   rp   = (int*)(wsb + (size_t)4 * 100352);        // N+1
    int*   cntm = (int*)(wsb + (size_t)4 * 200704);        // NBB
    int*   part = (int*)(wsb + (size_t)4 * 300800);        // 512
    float* U    = (float*)(wsb + (size_t)4 * 301312);      // 128
    float* E0t  = U + 128;                                 // 40
    float* E1t  = E0t + 40;                                // 40
    float* C    = E1t + 40;                                // 12
    float* Qs   = (float*)(wsb + (size_t)4 * 301568);      // 2N
    float* P    = (float*)(wsb + (size_t)4 * 501760);      // 2N
    bf16*  xWs  = (bf16*)(wsb + (size_t)4 * 702464);       // N*64 bf16 (12.8 MB)
    int*   col   = (int*)d_out;                            // E ints (first half)
    int*   pairs = (int*)d_out + E;                        // E ints (second half)
    // col+pairs = 2E ints = exactly out_size floats; k_edge overwrites last.

    k_small<<<1, 64, 0, stream>>>(W2, emb0, emb1, fcW1, fcb1, fcW2, fcb2,
                                  U, E0t, E1t, C);
    kA<<<NBLK, 256, 0, stream>>>(dst, cntm, E, chunk, NB);
    k_mscan1<<<BS, 256, 0, stream>>>(cntm, part, NBB);
    k_scan2<<<1, 512, 0, stream>>>(part, BS);
    k_mscan3<<<BS, 256, 0, stream>>>(cntm, part, NBB);
    kB<<<NBLK, 256, 0, stream>>>(src, dst, cntm, pairs, E, chunk, NB);
    kC<<<NB, 256, 0, stream>>>(cntm, pairs, col, rp, dinv, N, E, NB);
    k_gemm1<<<(N + 63) / 64, 256, 0, stream>>>(x, W1, dinv, xWs, N);
    k_gather1<<<((size_t)N * 64 + 255) / 256, 256, 0, stream>>>(xWs, dinv, rp, col, b1, U, Qs, N, E);
    k_gather2<<<(N + 255) / 256, 256, 0, stream>>>(dinv, rp, col, Qs, P, N);
    k_edge<<<(E + 255) / 256, 256, 0, stream>>>(src, dst, ea, P, E0t, E1t, C,
                                                (float*)d_out, E);
}